// Round 1
// baseline (154.929 us; speedup 1.0000x reference)
//
#include <hip/hip_runtime.h>

// Upscaler: out[b, t, h] with t = 4q + m:
//   t == 0        -> 0
//   t in 1..3     -> Z[b, 0, h]
//   t >= 4        -> (1 - 0.25*m) * Z[b, q-1, h] + (0.25*m) * Z[b, q, h]
// (weights from triangular kernel [0,.25,.5,.75,1,.75,.5,.25]; row sums == 1
//  exactly for t>=4, and +1e-8 is below half-ulp in fp32 -> exact identity)
//
// Shapes fixed by the harness: B=4, N=2048, H=1024, S=8192, fp32.

#define B_DIM 4
#define N_DIM 2048
#define H4    256    // H=1024 floats -> 256 float4
#define S_DIM 8192

__global__ __launch_bounds__(256)
void Upscaler_33294586479031_kernel(const float4* __restrict__ Z,
                                    float4* __restrict__ out) {
    const int bid = blockIdx.x;              // b * N_DIM + q
    const int q   = bid & (N_DIM - 1);
    const int b   = bid >> 11;               // / 2048
    const int h   = threadIdx.x;             // 0..255 -> float4 lane

    const float4* zb = Z + (size_t)b * N_DIM * H4;
    float4* ob = out + (size_t)b * S_DIM * H4 + (size_t)(4 * q) * H4 + h;

    const float4 zq = zb[(size_t)q * H4 + h];

    if (q == 0) {
        // t=0 -> zeros; t=1..3 -> Z[b,0,:] exactly
        float4 zero; zero.x = zero.y = zero.z = zero.w = 0.0f;
        ob[0 * H4] = zero;
        ob[1 * H4] = zq;
        ob[2 * H4] = zq;
        ob[3 * H4] = zq;
    } else {
        const float4 zp = zb[(size_t)(q - 1) * H4 + h];
        #pragma unroll
        for (int m = 0; m < 4; ++m) {
            const float w1 = 0.25f * (float)m;   // weight on Z[q]   (kernel[m])
            const float w0 = 1.0f - w1;          // weight on Z[q-1] (kernel[m+4])
            float4 r;
            r.x = w0 * zp.x + w1 * zq.x;
            r.y = w0 * zp.y + w1 * zq.y;
            r.z = w0 * zp.z + w1 * zq.z;
            r.w = w0 * zp.w + w1 * zq.w;
            ob[m * H4] = r;
        }
    }
}

extern "C" void kernel_launch(void* const* d_in, const int* in_sizes, int n_in,
                              void* d_out, int out_size, void* d_ws, size_t ws_size,
                              hipStream_t stream) {
    const float4* Z  = (const float4*)d_in[0];
    float4* out      = (float4*)d_out;

    const int grid = B_DIM * N_DIM;          // 8192 blocks
    Upscaler_33294586479031_kernel<<<grid, 256, 0, stream>>>(Z, out);
}